// Round 11
// baseline (233.476 us; speedup 1.0000x reference)
//
#include <hip/hip_runtime.h>
#include <hip/hip_bf16.h>
#include <stdint.h>

#define NE 8
#define HID 1024
#define FFN 4096
#define TOK 8192
#define TPE (TOK / NE)   // 1024 tokens per expert

typedef __attribute__((ext_vector_type(8))) short    bf16x8;
typedef __attribute__((ext_vector_type(4))) float    f32x4;
typedef __attribute__((ext_vector_type(4))) unsigned short ushort4v;
typedef __attribute__((ext_vector_type(8))) unsigned short ushort8v;

// ---------- helpers ----------

__device__ __forceinline__ unsigned short f2bf(float f) {
    union { float f; unsigned u; } c; c.f = f;
    unsigned r = c.u + 0x7fffu + ((c.u >> 16) & 1u);   // RNE, inputs finite
    return (unsigned short)(r >> 16);
}

__device__ __forceinline__ float gelu_tanh(float x) {
    const float c0 = 0.7978845608028654f;  // sqrt(2/pi)
    const float c1 = 0.044715f;
    float u = c0 * (x + c1 * x * x * x);
    float t = 1.0f - 2.0f / (1.0f + __expf(2.0f * u));
    return 0.5f * x * (1.0f + t);
}

typedef const __attribute__((address_space(1))) void gbl_void_t;
typedef __attribute__((address_space(3))) void lds_void_t;

__device__ __forceinline__ void gload_lds16(const void* g, void* l) {
    __builtin_amdgcn_global_load_lds((gbl_void_t*)g, (lds_void_t*)l, 16, 0, 0);
}

// ---------- merged prep: cvt x, cvt w1, transpose-cvt w2 (one launch) ------

#define XBLKS  ((TOK * HID) / 2048)              // 4096
#define W1BLKS ((NE * FFN * HID) / 2048)         // 16384
#define TBLKS  (NE * (FFN / 64) * (HID / 64))    // 8192

__global__ void prep_all(const float* __restrict__ x,  unsigned short* __restrict__ xb,
                         const float* __restrict__ w1, unsigned short* __restrict__ w1b,
                         const float* __restrict__ w2, unsigned short* __restrict__ w2t) {
    __shared__ unsigned short tile[64][65];
    int bid = blockIdx.x;
    if (bid < XBLKS + W1BLKS) {
        const float* in; unsigned short* out; size_t i;
        if (bid < XBLKS) { in = x;  out = xb;  i = ((size_t)bid * 256 + threadIdx.x) * 8; }
        else             { in = w1; out = w1b; i = ((size_t)(bid - XBLKS) * 256 + threadIdx.x) * 8; }
        f32x4 a = *(const f32x4*)(in + i);
        f32x4 b = *(const f32x4*)(in + i + 4);
        ushort8v o;
#pragma unroll
        for (int j = 0; j < 4; j++) { o[j] = f2bf(a[j]); o[4 + j] = f2bf(b[j]); }
        *(ushort8v*)(out + i) = o;
        return;
    }
    bid -= XBLKS + W1BLKS;
    const int e  = bid / ((FFN / 64) * (HID / 64));
    const int r_ = bid % ((FFN / 64) * (HID / 64));
    const int f0 = (r_ / (HID / 64)) * 64;
    const int h0 = (r_ % (HID / 64)) * 64;
    const float*     src = w2  + (size_t)e * FFN * HID;
    unsigned short*  dst = w2t + (size_t)e * HID * FFN;
    const int t  = threadIdx.x;
    const int tr = t >> 4;        // 0..15
    const int tc = (t & 15) * 4;  // 0..60
#pragma unroll
    for (int i = 0; i < 4; i++) {
        int f = i * 16 + tr;
        f32x4 v = *(const f32x4*)(src + (size_t)(f0 + f) * HID + h0 + tc);
#pragma unroll
        for (int j = 0; j < 4; j++) tile[f][tc + j] = f2bf(v[j]);
    }
    __syncthreads();
#pragma unroll
    for (int i = 0; i < 4; i++) {
        int h = i * 16 + tr;
        ushort4v o;
#pragma unroll
        for (int j = 0; j < 4; j++) o[j] = tile[tc + j][h];
        *(ushort4v*)(dst + (size_t)(h0 + h) * FFN + f0 + tc) = o;
    }
}

// ---------- 8-phase GEMM-BT (m201-faithful: zero pins, read-first) ---------
// C[M][N] = A[M][K] * B[N][K]^T per expert. BM=256, BK=64, 8 waves (2Mx4N),
// 512 threads, double-buffered LDS, T2 XOR swizzle (linear dest /
// pre-swizzled source / swizzled read), counted vmcnt at ph4/ph8 only,
// setprio around MFMA, T1 bijective XCD swizzle.
//
// R11 change: NO sched_barrier(0) anywhere (m201 template has none; R2's
// 6-pins/phase was the m141 failure mode and every variant since kept >=2).
// Safety: (a) MFMA operands are compiler-visible ds_read results -> data
// deps force correct lgkm waits even if MFMA hoists past the asm lgkmcnt;
// (b) stages and s_barrier are both side-effecting intrinsics -> not
// reordered; (c) ds_reads can't hoist above VMW (asm memory clobber) and
// all other publishes are >=2 barriers upstream (FIFO traced, R3-validated
// stream). Phase = {reads; stage-unit; barrier; lgkm0; setprio MFMA; barrier}.
// Stage slots uniform 1 unit/phase: ph1:A1(T+1) ph2:A0(T+2) ph3:B0(T+2)
// ph4:B1(T+2)+VMW, mirrored for ph5-8. VMC = 3 units in flight.

template <int BN, int GX, int GY, bool GELU>
__global__ __launch_bounds__(512, 2)
void gemm8p(const unsigned short* __restrict__ A,
            const unsigned short* __restrict__ B,
            void* __restrict__ Cout, int M, int N, int K) {
    constexpr int BM = 256, BK = 64;
    constexpr int NH = BN / 128;          // n-frags per quad (2 or 1)
    constexpr int NI = 2 * NH;            // n-frags per wave
    constexpr int LB = BN / 128;          // loads per B-unit per thread
    constexpr int S  = BN / 8;            // B-unit row-group half-stride
    constexpr int ABYTES = BM * BK * 2;   // 32768
    constexpr int BBYTES = BN * BK * 2;   // 32768 / 16384
    constexpr int BUF = ABYTES + BBYTES;
    constexpr int VMC = 2 + 2 * LB;       // 6 (BN=256) or 4 (BN=128)
    constexpr int NWG = NE * GX * GY;     // flat grid size (multiple of 8)

    __shared__ __align__(16) char lds[2 * BUF];

    // ---- XCD-aware bijective swizzle (T1) ----
    const int lin = blockIdx.x;
    const int wid = (lin & 7) * (NWG >> 3) + (lin >> 3);
    const int e   = wid / (GX * GY);
    const int rem = wid % (GX * GY);
    const int m0  = (rem % GX) * BM;
    const int n0  = (rem / GX) * BN;

    const size_t K2 = (size_t)K * 2;
    const char* Ae = (const char*)(A + (size_t)e * M * K);
    const char* Be = (const char*)(B + (size_t)e * N * K);

    const int tid  = threadIdx.x;
    const int lane = tid & 63;
    const int w    = tid >> 6;
    const int wr   = w >> 2, wc = w & 3;
    const int fr   = lane & 15, fq = lane >> 4;

    // ---- staging addressing (rule #21: linear LDS dest, pre-swizzled src) ----
    const int rA  = tid >> 3;             // 0..63
    const int kb  = (tid & 7) * 16;       // byte offset in 128B row
    const int kbs = kb ^ ((rA & 7) << 4); // swizzled source k-offset
    const char* aptr = Ae + (size_t)(m0 + rA) * K2 + kbs;
    const int   fB   = (rA / S) * 2 * S + (rA % S);
    const char* bptr = Be + (size_t)(n0 + fB) * K2 + kbs;
    char* dA0 = lds + rA * 128 + kb;      // wave-linear dest (base + lane*16)
    char* dA1 = dA0 + BUF;
    char* dB0 = lds + ABYTES + fB * 128 + kb;
    char* dB1 = dB0 + BUF;

    auto SA = [&](int au, int kt, char* d) {      // stage A-unit au of tile kt
        const char* s = aptr + (size_t)kt * 128;
#pragma unroll
        for (int i = 0; i < 2; i++)
            gload_lds16(s + (size_t)(au * 64 + i * 128) * K2,
                        d + (au * 64 + i * 128) * 128);
    };
    auto SB = [&](int bu, int kt, char* d) {      // stage B-unit bu of tile kt
        const char* s = bptr + (size_t)kt * 128;
#pragma unroll
        for (int i = 0; i < LB; i++)
            gload_lds16(s + (size_t)(bu * S + i * 128) * K2,
                        d + (bu * S + i * 128) * 128);
    };

    // ---- LDS read base pointers (swizzled reads) ----
    const int kx0 = (fq * 16) ^ ((lane & 7) << 4);
    const char* paA = lds + (wr * 128 + fr) * 128;
    const char* paB = lds + ABYTES + (wc * (BN / 4) + fr) * 128;
    const char* pa0k0 = paA + kx0;        const char* pa0k1 = paA + (kx0 ^ 64);
    const char* pa1k0 = pa0k0 + BUF;      const char* pa1k1 = pa0k1 + BUF;
    const char* pb0k0 = paB + kx0;        const char* pb0k1 = paB + (kx0 ^ 64);
    const char* pb1k0 = pb0k0 + BUF;      const char* pb1k1 = pb0k1 + BUF;

    f32x4 acc[8][NI];
#pragma unroll
    for (int i = 0; i < 8; i++)
#pragma unroll
        for (int j = 0; j < NI; j++) acc[i][j] = f32x4{0.f, 0.f, 0.f, 0.f};

    bf16x8 a[4][2], b0[NH][2], b1[NH][2];

    auto LDA = [&](const char* p0, const char* p1, int mq) {
#pragma unroll
        for (int mi = 0; mi < 4; mi++) {
            a[mi][0] = *(const bf16x8*)(p0 + mq * 8192 + mi * 2048);
            a[mi][1] = *(const bf16x8*)(p1 + mq * 8192 + mi * 2048);
        }
    };
    auto LDB = [&](const char* p0, const char* p1, int nq, bf16x8 (&bb)[NH][2]) {
#pragma unroll
        for (int ni = 0; ni < NH; ni++) {
            bb[ni][0] = *(const bf16x8*)(p0 + (nq * (BN / 8) + ni * 16) * 128);
            bb[ni][1] = *(const bf16x8*)(p1 + (nq * (BN / 8) + ni * 16) * 128);
        }
    };
    auto MMQ = [&](int mq, int nq, bf16x8 (&bb)[NH][2]) {
        __builtin_amdgcn_s_setprio(1);
#pragma unroll
        for (int mi = 0; mi < 4; mi++)
#pragma unroll
            for (int ni = 0; ni < NH; ni++) {
                f32x4& c = acc[mq * 4 + mi][nq * NH + ni];
                c = __builtin_amdgcn_mfma_f32_16x16x32_bf16(a[mi][0], bb[ni][0], c, 0, 0, 0);
                c = __builtin_amdgcn_mfma_f32_16x16x32_bf16(a[mi][1], bb[ni][1], c, 0, 0, 0);
            }
        __builtin_amdgcn_s_setprio(0);
    };

    // m201-faithful sync: no sched_barrier pins anywhere.
#define MIDBAR()  __builtin_amdgcn_s_barrier();                                      \
                  asm volatile("s_waitcnt lgkmcnt(0)" ::: "memory")
#define ENDBAR()  __builtin_amdgcn_s_barrier()
#define LGHINT()  asm volatile("s_waitcnt lgkmcnt(8)" ::: "memory")
#define VMW()     asm volatile("s_waitcnt vmcnt(%0)" :: "n"(VMC) : "memory")

    const int NT   = K / BK;
    const int NTm1 = NT - 1;

    // prologue: tile0 all units, tile1 {A0,B0,B1}; drain tile0, keep 3 units
    SA(0, 0, dA0); SB(0, 0, dB0); SB(1, 0, dB0); SA(1, 0, dA0);
    SA(0, 1, dA1); SB(0, 1, dB1); SB(1, 1, dB1);
    VMW();
    __builtin_amdgcn_s_barrier();

    const int NW = NT / 2;
    for (int ww = 0; ww < NW; ++ww) {
        const int T = 2 * ww;
        const int kt1 = T + 1;                          // always < NT
        const int kt2 = (T + 2 < NT) ? T + 2 : NTm1;
        const int kt3 = (T + 3 < NT) ? T + 3 : NTm1;

        // ---- buf0 half: tile T ----
        LDA(pa0k0, pa0k1, 0); LDB(pb0k0, pb0k1, 0, b0); SA(1, kt1, dA1); LGHINT();
        MIDBAR(); MMQ(0, 0, b0); ENDBAR();                       // ph1
        LDB(pb0k0, pb0k1, 1, b1); SA(0, kt2, dA0);
        MIDBAR(); MMQ(0, 1, b1); ENDBAR();                       // ph2
        LDA(pa0k0, pa0k1, 1); SB(0, kt2, dB0);
        MIDBAR(); MMQ(1, 1, b1); ENDBAR();                       // ph3
        SB(1, kt2, dB0);
        MIDBAR(); MMQ(1, 0, b0); VMW(); ENDBAR();                // ph4
        // ---- buf1 half: tile T+1 ----
        LDA(pa1k0, pa1k1, 0); LDB(pb1k0, pb1k1, 0, b0); SA(1, kt2, dA0); LGHINT();
        MIDBAR(); MMQ(0, 0, b0); ENDBAR();                       // ph5
        LDB(pb1k0, pb1k1, 1, b1); SA(0, kt3, dA1);
        MIDBAR(); MMQ(0, 1, b1); ENDBAR();                       // ph6
        LDA(pa1k0, pa1k1, 1); SB(0, kt3, dB1);
        MIDBAR(); MMQ(1, 1, b1); ENDBAR();                       // ph7
        SB(1, kt3, dB1);
        MIDBAR(); MMQ(1, 0, b0); VMW(); ENDBAR();                // ph8
    }
    asm volatile("s_waitcnt vmcnt(0)" ::: "memory");   // drain tail junk stages

    // epilogue: C/D layout col = lane&15, row = (lane>>4)*4 + r
    const int r0 = m0 + wr * 128 + fq * 4;
    const int c0 = n0 + wc * (BN / 4) + fr;
    if constexpr (GELU) {
        unsigned short* C = (unsigned short*)Cout + (size_t)e * M * N;
#pragma unroll
        for (int mi = 0; mi < 8; mi++)
#pragma unroll
            for (int ni = 0; ni < NI; ni++) {
                int row = r0 + mi * 16, col = c0 + ni * 16;
#pragma unroll
                for (int r = 0; r < 4; r++)
                    C[(size_t)(row + r) * N + col] = f2bf(gelu_tanh(acc[mi][ni][r]));
            }
    } else {
        float* C = (float*)Cout + (size_t)e * M * N;
#pragma unroll
        for (int mi = 0; mi < 8; mi++)
#pragma unroll
            for (int ni = 0; ni < NI; ni++) {
                int row = r0 + mi * 16, col = c0 + ni * 16;
#pragma unroll
                for (int r = 0; r < 4; r++)
                    C[(size_t)(row + r) * N + col] = acc[mi][ni][r];
            }
    }
#undef MIDBAR
#undef ENDBAR
#undef LGHINT
#undef VMW
}

// ---------- fallback: fused fp32, zero workspace (correctness insurance) ----------

__global__ void fused_fallback(const float* __restrict__ x,
                               const float* __restrict__ w1,
                               const float* __restrict__ w2,
                               float* __restrict__ out) {
    __shared__ float xs[HID];
    __shared__ float hs[FFN];
    const int tok = blockIdx.x;
    const int e   = tok / TPE;
    const float* w1e = w1 + (size_t)e * FFN * HID;
    const float* w2e = w2 + (size_t)e * FFN * HID;
    const int t = threadIdx.x;
    for (int i = t; i < HID; i += 256) xs[i] = x[(size_t)tok * HID + i];
    __syncthreads();
    for (int f = t; f < FFN; f += 256) {
        const float* wr_ = w1e + (size_t)f * HID;
        float s = 0.f;
        for (int k = 0; k < HID; k++) s += xs[k] * wr_[k];
        hs[f] = gelu_tanh(s);
    }
    __syncthreads();
    for (int h = t; h < HID; h += 256) {
        float s = 0.f;
        for (int f = 0; f < FFN; f++) s += hs[f] * w2e[(size_t)f * HID + h];
        out[(size_t)tok * HID + h] = s;
    }
}

// ---------- launch ----------

extern "C" void kernel_launch(void* const* d_in, const int* in_sizes, int n_in,
                              void* d_out, int out_size, void* d_ws, size_t ws_size,
                              hipStream_t stream) {
    const float* x  = (const float*)d_in[0];
    const float* w1 = (const float*)d_in[1];
    const float* w2 = (const float*)d_in[2];
    float* out = (float*)d_out;

    const size_t XB  = (size_t)TOK * HID * 2;        // 16 MB  bf16 x
    const size_t W1B = (size_t)NE * FFN * HID * 2;   // 64 MB  bf16 w1
    const size_t W2B = W1B;                          // 64 MB  bf16 w2t
    const size_t HB  = (size_t)TOK * FFN * 2;        // 64 MB  bf16 h
    const size_t need = XB + W1B + W2B + HB;         // 208 MB

    if (ws_size >= need) {
        char* ws = (char*)d_ws;
        unsigned short* xb  = (unsigned short*)ws;
        unsigned short* w1b = (unsigned short*)(ws + XB);
        unsigned short* w2t = (unsigned short*)(ws + XB + W1B);
        unsigned short* hb  = (unsigned short*)(ws + XB + W1B + W2B);

        prep_all<<<XBLKS + W1BLKS + TBLKS, 256, 0, stream>>>(x, xb, w1, w1b, w2, w2t);

        // GEMM1: h = gelu(x @ w1^T)  M=1024,N=4096,K=1024/expert -> 512 blocks flat
        gemm8p<256, TPE / 256, FFN / 256, true><<<NE * (TPE / 256) * (FFN / 256), 512, 0, stream>>>(
            xb, w1b, hb, TPE, FFN, HID);
        // GEMM2: out = h @ w2t^T     M=1024,N=1024,K=4096/expert -> 256 blocks flat
        gemm8p<128, TPE / 256, HID / 128, false><<<NE * (TPE / 256) * (HID / 128), 512, 0, stream>>>(
            hb, w2t, out, TPE, HID, FFN);
    } else {
        fused_fallback<<<TOK, 256, 0, stream>>>(x, w1, w2, out);
    }
}